// Round 3
// baseline (5010.345 us; speedup 1.0000x reference)
//
#include <hip/hip_runtime.h>

#define N_NODES   100000
#define D_IN      512
#define NUM_CODES 2048
#define D_OUT     256
#define K_SEL     4

__device__ __forceinline__ bool better(float s, int i, float S, int I) {
  return (s < S) || (s == S && i < I);
}

// ---------------------------------------------------------------------------
// numpy pairwise sum of squares over a contiguous row of 512 floats.
// Replicates numpy's pairwise_sum exactly for n=512:
//   S(512) = (S(0:128)+S(128:256)) + (S(256:384)+S(384:512))
//   S(128-block): r[j] = a[j]*a[j]; 15x r[j] += a[8i+j]*a[8i+j];
//                 ((r0+r1)+(r2+r3)) + ((r4+r5)+(r6+r7))
// Products are rounded fp32 BEFORE adding (np materializes h*h) -> __fmul_rn
// + __fadd_rn, never fused.
// ---------------------------------------------------------------------------
__device__ __forceinline__ float np_pairwise_sq512(const float* __restrict__ a) {
  float tot[4];
#pragma unroll
  for (int b = 0; b < 4; b++) {
    const float* p = a + (b << 7);
    float r[8];
    {
      float4 q0 = *(const float4*)(p);
      float4 q1 = *(const float4*)(p + 4);
      r[0] = __fmul_rn(q0.x, q0.x); r[1] = __fmul_rn(q0.y, q0.y);
      r[2] = __fmul_rn(q0.z, q0.z); r[3] = __fmul_rn(q0.w, q0.w);
      r[4] = __fmul_rn(q1.x, q1.x); r[5] = __fmul_rn(q1.y, q1.y);
      r[6] = __fmul_rn(q1.z, q1.z); r[7] = __fmul_rn(q1.w, q1.w);
    }
    for (int i = 8; i < 128; i += 8) {
      float4 u0 = *(const float4*)(p + i);
      float4 u1 = *(const float4*)(p + i + 4);
      r[0] = __fadd_rn(r[0], __fmul_rn(u0.x, u0.x));
      r[1] = __fadd_rn(r[1], __fmul_rn(u0.y, u0.y));
      r[2] = __fadd_rn(r[2], __fmul_rn(u0.z, u0.z));
      r[3] = __fadd_rn(r[3], __fmul_rn(u0.w, u0.w));
      r[4] = __fadd_rn(r[4], __fmul_rn(u1.x, u1.x));
      r[5] = __fadd_rn(r[5], __fmul_rn(u1.y, u1.y));
      r[6] = __fadd_rn(r[6], __fmul_rn(u1.z, u1.z));
      r[7] = __fadd_rn(r[7], __fmul_rn(u1.w, u1.w));
    }
    float t01 = __fadd_rn(r[0], r[1]);
    float t23 = __fadd_rn(r[2], r[3]);
    float t45 = __fadd_rn(r[4], r[5]);
    float t67 = __fadd_rn(r[6], r[7]);
    tot[b] = __fadd_rn(__fadd_rn(t01, t23), __fadd_rn(t45, t67));
  }
  return __fadd_rn(__fadd_rn(tot[0], tot[1]), __fadd_rn(tot[2], tot[3]));
}

// one thread per row: out[r] = np.sum(A[r]*A[r]) (numpy pairwise)
__global__ __launch_bounds__(256) void k_rowsq(const float* __restrict__ A,
                                               int nrows,
                                               float* __restrict__ out) {
  int r = blockIdx.x * 256 + threadIdx.x;
  if (r >= nrows) return;
  out[r] = np_pairwise_sq512(A + (size_t)r * D_IN);
}

// ---------------------------------------------------------------------------
// H = X @ LP, fp32, SINGLE sequential k-order FMA chain per output element
// (replicates BLAS rank-1-update accumulation order).
// ---------------------------------------------------------------------------
__global__ __launch_bounds__(256) void k_h_np(const float* __restrict__ X,
                                              const float* __restrict__ W,
                                              float* __restrict__ H) {
  __shared__ float As[16][68];  // As[k][m]
  __shared__ float Bs[16][68];  // Bs[k][n]
  const int tid = threadIdx.x;
  const int row0 = blockIdx.x * 64;
  const int col0 = blockIdx.y * 64;
  const int ty = tid >> 4, tx = tid & 15;
  const int am = tid >> 2, ak = (tid & 3) << 2;
  const int bk = tid >> 4, bn = (tid & 15) << 2;
  float acc[4][4] = {};
  for (int k0 = 0; k0 < D_IN; k0 += 16) {
    float4 av = make_float4(0.f, 0.f, 0.f, 0.f);
    if (row0 + am < N_NODES)
      av = *(const float4*)(X + (size_t)(row0 + am) * D_IN + k0 + ak);
    float4 bv = *(const float4*)(W + (size_t)(k0 + bk) * D_IN + col0 + bn);
    __syncthreads();
    As[ak + 0][am] = av.x; As[ak + 1][am] = av.y;
    As[ak + 2][am] = av.z; As[ak + 3][am] = av.w;
    *(float4*)&Bs[bk][bn] = bv;
    __syncthreads();
#pragma unroll
    for (int kk = 0; kk < 16; kk++) {  // strictly increasing k: single chain
      float4 a = *(const float4*)&As[kk][ty << 2];
      float4 b = *(const float4*)&Bs[kk][tx << 2];
      float aa[4] = {a.x, a.y, a.z, a.w};
      float bb[4] = {b.x, b.y, b.z, b.w};
#pragma unroll
      for (int i = 0; i < 4; i++)
#pragma unroll
        for (int j = 0; j < 4; j++) acc[i][j] = fmaf(aa[i], bb[j], acc[i][j]);
    }
  }
#pragma unroll
  for (int i = 0; i < 4; i++) {
    int r = row0 + (ty << 2) + i;
    if (r < N_NODES)
      *(float4*)(H + (size_t)r * D_IN + col0 + (tx << 2)) =
          make_float4(acc[i][0], acc[i][1], acc[i][2], acc[i][3]);
  }
}

// ---------------------------------------------------------------------------
// P[c][o] = CB[c]·HW[:,o] in fp64 (stored fp32). Logit path only; selection
// unaffected. logits row = 0.25*sum P[sel] + bias (error ~1e-6 << 2.7e-3).
// ---------------------------------------------------------------------------
__global__ __launch_bounds__(256) void k_gemm_P(const float* __restrict__ CB,
                                                const float* __restrict__ HW,
                                                float* __restrict__ P) {
  __shared__ float As[16][68];
  __shared__ float Bs[16][68];
  const int tid = threadIdx.x;
  const int c0 = blockIdx.x * 64;
  const int o0 = blockIdx.y * 64;
  const int ty = tid >> 4, tx = tid & 15;
  const int am = tid >> 2, ak = (tid & 3) << 2;
  const int bk = tid >> 4, bn = (tid & 15) << 2;
  double acc[4][4] = {};
  for (int k0 = 0; k0 < D_IN; k0 += 16) {
    float4 av = *(const float4*)(CB + (size_t)(c0 + am) * D_IN + k0 + ak);
    float4 bv = *(const float4*)(HW + (size_t)(k0 + bk) * D_OUT + o0 + bn);
    __syncthreads();
    As[ak + 0][am] = av.x; As[ak + 1][am] = av.y;
    As[ak + 2][am] = av.z; As[ak + 3][am] = av.w;
    *(float4*)&Bs[bk][bn] = bv;
    __syncthreads();
#pragma unroll
    for (int kk = 0; kk < 16; kk++) {
      float4 a = *(const float4*)&As[kk][ty << 2];
      float4 b = *(const float4*)&Bs[kk][tx << 2];
      double aa[4] = {a.x, a.y, a.z, a.w};
      double bb[4] = {b.x, b.y, b.z, b.w};
#pragma unroll
      for (int i = 0; i < 4; i++)
#pragma unroll
        for (int j = 0; j < 4; j++) acc[i][j] = fma(aa[i], bb[j], acc[i][j]);
    }
  }
#pragma unroll
  for (int i = 0; i < 4; i++)
#pragma unroll
    for (int j = 0; j < 4; j++)
      P[(size_t)(c0 + (ty << 2) + i) * D_OUT + o0 + (tx << 2) + j] =
          (float)acc[i][j];
}

// ---------------------------------------------------------------------------
// Fast pass, np-exact: hd chains in strict k order (fp32 fmaf), score =
// fl(fl(h_sq - fl(2*hd)) + cb_sq), top-4 per row, ties -> lower index.
// 64 rows x 128-code tiles.
// ---------------------------------------------------------------------------
__global__ __launch_bounds__(256) void k_fastpass(const float* __restrict__ H,
                                                  const float* __restrict__ CB,
                                                  const float* __restrict__ CBSQ,
                                                  const float* __restrict__ HSQ,
                                                  int* __restrict__ cand) {
  __shared__ float Hs[16][68];    // Hs[k][row]
  __shared__ float Cs[16][136];   // Cs[k][code]
  __shared__ float Sc[64][129];   // scores for this 128-code tile
  __shared__ float Mf[64][17];
  __shared__ int   Mi[64][17];
  const int tid = threadIdx.x;
  const int row0 = blockIdx.x * 64;
  const int ty = tid >> 4, tx = tid & 15;
  const int am = tid >> 2, ak = (tid & 3) << 2;
  const int cr = tid >> 1, ck = (tid & 1) << 3;
  const int srow = tid & 63, sslot = tid >> 6;

  float hq[4];
#pragma unroll
  for (int i = 0; i < 4; i++) {
    int r = row0 + (ty << 2) + i;
    hq[i] = (r < N_NODES) ? HSQ[r] : 0.f;
  }

  float rs[K_SEL]; int ri[K_SEL];
#pragma unroll
  for (int k = 0; k < K_SEL; k++) { rs[k] = 3.4e38f; ri[k] = 0x7fffffff; }

  for (int ct = 0; ct < NUM_CODES / 128; ct++) {
    const int c0 = ct * 128;
    float acc[4][8] = {};
    float cq[8];
#pragma unroll
    for (int j = 0; j < 8; j++) cq[j] = CBSQ[c0 + (tx << 3) + j];

    for (int k0 = 0; k0 < D_IN; k0 += 16) {
      float4 hv = make_float4(0.f, 0.f, 0.f, 0.f);
      if (row0 + am < N_NODES)
        hv = *(const float4*)(H + (size_t)(row0 + am) * D_IN + k0 + ak);
      float4 ca  = *(const float4*)(CB + (size_t)(c0 + cr) * D_IN + k0 + ck);
      float4 cb4 = *(const float4*)(CB + (size_t)(c0 + cr) * D_IN + k0 + ck + 4);
      __syncthreads();
      Hs[ak + 0][am] = hv.x; Hs[ak + 1][am] = hv.y;
      Hs[ak + 2][am] = hv.z; Hs[ak + 3][am] = hv.w;
      Cs[ck + 0][cr] = ca.x;  Cs[ck + 1][cr] = ca.y;
      Cs[ck + 2][cr] = ca.z;  Cs[ck + 3][cr] = ca.w;
      Cs[ck + 4][cr] = cb4.x; Cs[ck + 5][cr] = cb4.y;
      Cs[ck + 6][cr] = cb4.z; Cs[ck + 7][cr] = cb4.w;
      __syncthreads();
#pragma unroll
      for (int kk = 0; kk < 16; kk++) {  // strict k order: single FMA chain
        float4 h4  = *(const float4*)&Hs[kk][ty << 2];
        float4 c4a = *(const float4*)&Cs[kk][tx << 3];
        float4 c4b = *(const float4*)&Cs[kk][(tx << 3) + 4];
        float hh[4] = {h4.x, h4.y, h4.z, h4.w};
        float cc[8] = {c4a.x, c4a.y, c4a.z, c4a.w, c4b.x, c4b.y, c4b.z, c4b.w};
#pragma unroll
        for (int i = 0; i < 4; i++)
#pragma unroll
          for (int j = 0; j < 8; j++)
            acc[i][j] = fmaf(hh[i], cc[j], acc[i][j]);
      }
    }
    __syncthreads();
#pragma unroll
    for (int i = 0; i < 4; i++)
#pragma unroll
      for (int j = 0; j < 8; j++) {
        // np: dist = (h_sq - 2.0*hd) + cb_sq, each step rounded fp32
        float t = __fsub_rn(hq[i], 2.0f * acc[i][j]);  // 2*hd exact
        Sc[(ty << 2) + i][(tx << 3) + j] = __fadd_rn(t, cq[j]);
      }
    __syncthreads();
    const int cbase = c0 + (sslot << 5);
    for (int j = 0; j < 32; j++) {
      float s = Sc[srow][(sslot << 5) + j];
      int c = cbase + j;
      if (better(s, c, rs[K_SEL - 1], ri[K_SEL - 1])) {
        rs[K_SEL - 1] = s; ri[K_SEL - 1] = c;
#pragma unroll
        for (int t = K_SEL - 1; t > 0; t--) {
          if (better(rs[t], ri[t], rs[t - 1], ri[t - 1])) {
            float tf = rs[t - 1]; rs[t - 1] = rs[t]; rs[t] = tf;
            int tc = ri[t - 1]; ri[t - 1] = ri[t]; ri[t] = tc;
          }
        }
      }
    }
    __syncthreads();
  }
#pragma unroll
  for (int k = 0; k < K_SEL; k++) {
    Mf[srow][sslot * K_SEL + k] = rs[k];
    Mi[srow][sslot * K_SEL + k] = ri[k];
  }
  __syncthreads();
  if (tid < 64) {
    int row = row0 + tid;
    if (row < N_NODES) {
      float bs[K_SEL]; int bi[K_SEL];
#pragma unroll
      for (int k = 0; k < K_SEL; k++) { bs[k] = 3.4e38f; bi[k] = 0x7fffffff; }
      for (int e = 0; e < 4 * K_SEL; e++) {
        float s = Mf[tid][e]; int c = Mi[tid][e];
        if (better(s, c, bs[K_SEL - 1], bi[K_SEL - 1])) {
          bs[K_SEL - 1] = s; bi[K_SEL - 1] = c;
#pragma unroll
          for (int t = K_SEL - 1; t > 0; t--) {
            if (better(bs[t], bi[t], bs[t - 1], bi[t - 1])) {
              float tf = bs[t - 1]; bs[t - 1] = bs[t]; bs[t] = tf;
              int tc = bi[t - 1]; bi[t - 1] = bi[t]; bi[t] = tc;
            }
          }
        }
      }
#pragma unroll
      for (int k = 0; k < K_SEL; k++) cand[(size_t)row * K_SEL + k] = bi[k];
    }
  }
}

// ---------------------------------------------------------------------------
// OUT[row] = 0.25 * (P[c0]+P[c1]+P[c2]+P[c3]) + bias.  One wave per row.
// ---------------------------------------------------------------------------
__global__ __launch_bounds__(256) void k_out(const int* __restrict__ cand,
                                             const float* __restrict__ P,
                                             const float* __restrict__ HB,
                                             float* __restrict__ OUT) {
  const int lane = threadIdx.x & 63;
  const int row = blockIdx.x * 4 + (threadIdx.x >> 6);
  if (row >= N_NODES) return;
  const int c0 = cand[(size_t)row * K_SEL + 0];
  const int c1 = cand[(size_t)row * K_SEL + 1];
  const int c2 = cand[(size_t)row * K_SEL + 2];
  const int c3 = cand[(size_t)row * K_SEL + 3];
  const int col = lane << 2;
  float4 p0 = *(const float4*)(P + (size_t)c0 * D_OUT + col);
  float4 p1 = *(const float4*)(P + (size_t)c1 * D_OUT + col);
  float4 p2 = *(const float4*)(P + (size_t)c2 * D_OUT + col);
  float4 p3 = *(const float4*)(P + (size_t)c3 * D_OUT + col);
  float4 b = *(const float4*)(HB + col);
  float4 o;
  o.x = 0.25f * (((p0.x + p1.x) + p2.x) + p3.x) + b.x;
  o.y = 0.25f * (((p0.y + p1.y) + p2.y) + p3.y) + b.y;
  o.z = 0.25f * (((p0.z + p1.z) + p2.z) + p3.z) + b.z;
  o.w = 0.25f * (((p0.w + p1.w) + p2.w) + p3.w) + b.w;
  *(float4*)(OUT + (size_t)row * D_OUT + col) = o;
}

// ---------------------------------------------------------------------------
extern "C" void kernel_launch(void* const* d_in, const int* in_sizes, int n_in,
                              void* d_out, int out_size, void* d_ws,
                              size_t ws_size, hipStream_t stream) {
  const float* X  = (const float*)d_in[0];
  const float* LP = (const float*)d_in[1];
  const float* CB = (const float*)d_in[2];
  const float* HW = (const float*)d_in[3];
  const float* HB = (const float*)d_in[4];
  float* OUT = (float*)d_out;

  char* ws = (char*)d_ws;
  size_t off = 0;
  float* H = (float*)(ws + off);     off += (size_t)N_NODES * D_IN * 4;    // 204.8 MB
  float* P = (float*)(ws + off);     off += (size_t)NUM_CODES * D_OUT * 4; // 2 MB
  float* CBSQ = (float*)(ws + off);  off += (size_t)NUM_CODES * 4;
  float* HSQ = (float*)(ws + off);   off += (size_t)N_NODES * 4;
  off = (off + 255) & ~(size_t)255;
  int* cand = (int*)(ws + off);      off += (size_t)N_NODES * K_SEL * 4;
  // total ~209 MB (round-1's 421 MB layout ran without corruption)

  const int row_blocks = (N_NODES + 63) / 64;

  k_rowsq<<<(NUM_CODES + 255) / 256, 256, 0, stream>>>(CB, NUM_CODES, CBSQ);
  k_gemm_P<<<dim3(NUM_CODES / 64, D_OUT / 64), 256, 0, stream>>>(CB, HW, P);
  k_h_np<<<dim3(row_blocks, D_IN / 64), 256, 0, stream>>>(X, LP, H);
  k_rowsq<<<(N_NODES + 255) / 256, 256, 0, stream>>>(H, N_NODES, HSQ);
  k_fastpass<<<row_blocks, 256, 0, stream>>>(H, CB, CBSQ, HSQ, cand);
  k_out<<<N_NODES / 4, 256, 0, stream>>>(cand, P, HB, OUT);
}

// Round 4
// 2617.238 us; speedup vs baseline: 1.9144x; 1.9144x over previous
//
#include <hip/hip_runtime.h>

#define N_NODES   100000
#define D_IN      512
#define NUM_CODES 2048
#define D_OUT     256
#define NCAND     16
#define RESCORE_MARGIN 0.05f

typedef float f32x4  __attribute__((ext_vector_type(4)));
typedef short bf16x8 __attribute__((ext_vector_type(8)));

__device__ __forceinline__ bool better(float s, int i, float S, int I) {
  return (s < S) || (s == S && i < I);
}

__device__ __forceinline__ unsigned short f2bf(float f) {
  unsigned int u = __float_as_uint(f);
  u = (u + 0x7fffu + ((u >> 16) & 1u)) >> 16;  // RNE
  return (unsigned short)u;
}

// ---------------------------------------------------------------------------
// numpy pairwise sum-of-squares over a 512-float row (np-exact; see r3).
// ---------------------------------------------------------------------------
__device__ __forceinline__ float np_pairwise_sq512(const float* __restrict__ a) {
  float tot[4];
#pragma unroll
  for (int b = 0; b < 4; b++) {
    const float* p = a + (b << 7);
    float r[8];
    {
      float4 q0 = *(const float4*)(p);
      float4 q1 = *(const float4*)(p + 4);
      r[0] = __fmul_rn(q0.x, q0.x); r[1] = __fmul_rn(q0.y, q0.y);
      r[2] = __fmul_rn(q0.z, q0.z); r[3] = __fmul_rn(q0.w, q0.w);
      r[4] = __fmul_rn(q1.x, q1.x); r[5] = __fmul_rn(q1.y, q1.y);
      r[6] = __fmul_rn(q1.z, q1.z); r[7] = __fmul_rn(q1.w, q1.w);
    }
    for (int i = 8; i < 128; i += 8) {
      float4 u0 = *(const float4*)(p + i);
      float4 u1 = *(const float4*)(p + i + 4);
      r[0] = __fadd_rn(r[0], __fmul_rn(u0.x, u0.x));
      r[1] = __fadd_rn(r[1], __fmul_rn(u0.y, u0.y));
      r[2] = __fadd_rn(r[2], __fmul_rn(u0.z, u0.z));
      r[3] = __fadd_rn(r[3], __fmul_rn(u0.w, u0.w));
      r[4] = __fadd_rn(r[4], __fmul_rn(u1.x, u1.x));
      r[5] = __fadd_rn(r[5], __fmul_rn(u1.y, u1.y));
      r[6] = __fadd_rn(r[6], __fmul_rn(u1.z, u1.z));
      r[7] = __fadd_rn(r[7], __fmul_rn(u1.w, u1.w));
    }
    float t01 = __fadd_rn(r[0], r[1]);
    float t23 = __fadd_rn(r[2], r[3]);
    float t45 = __fadd_rn(r[4], r[5]);
    float t67 = __fadd_rn(r[6], r[7]);
    tot[b] = __fadd_rn(__fadd_rn(t01, t23), __fadd_rn(t45, t67));
  }
  return __fadd_rn(__fadd_rn(tot[0], tot[1]), __fadd_rn(tot[2], tot[3]));
}

__global__ __launch_bounds__(256) void k_rowsq(const float* __restrict__ A,
                                               int nrows,
                                               float* __restrict__ out) {
  int r = blockIdx.x * 256 + threadIdx.x;
  if (r >= nrows) return;
  out[r] = np_pairwise_sq512(A + (size_t)r * D_IN);
}

// ---------------------------------------------------------------------------
// CBb = bf16(CB)
// ---------------------------------------------------------------------------
__global__ __launch_bounds__(256) void k_cb2bf(const float* __restrict__ CB,
                                               unsigned short* __restrict__ CBb) {
  int idx = (blockIdx.x * 256 + threadIdx.x) * 4;
  float4 v = *(const float4*)(CB + idx);
  ushort4 s;
  s.x = f2bf(v.x); s.y = f2bf(v.y); s.z = f2bf(v.z); s.w = f2bf(v.w);
  *(ushort4*)(CBb + idx) = s;
}

// ---------------------------------------------------------------------------
// H = X @ LP (np-exact fp32, single sequential-k FMA chain; verified r3).
// Also emits Hb = bf16(H) for the MFMA candidate pass.
// ---------------------------------------------------------------------------
__global__ __launch_bounds__(256) void k_h_np(const float* __restrict__ X,
                                              const float* __restrict__ W,
                                              float* __restrict__ H,
                                              unsigned short* __restrict__ Hb) {
  __shared__ float As[16][68];
  __shared__ float Bs[16][68];
  const int tid = threadIdx.x;
  const int row0 = blockIdx.x * 64;
  const int col0 = blockIdx.y * 64;
  const int ty = tid >> 4, tx = tid & 15;
  const int am = tid >> 2, ak = (tid & 3) << 2;
  const int bk = tid >> 4, bn = (tid & 15) << 2;
  float acc[4][4] = {};
  for (int k0 = 0; k0 < D_IN; k0 += 16) {
    float4 av = make_float4(0.f, 0.f, 0.f, 0.f);
    if (row0 + am < N_NODES)
      av = *(const float4*)(X + (size_t)(row0 + am) * D_IN + k0 + ak);
    float4 bv = *(const float4*)(W + (size_t)(k0 + bk) * D_IN + col0 + bn);
    __syncthreads();
    As[ak + 0][am] = av.x; As[ak + 1][am] = av.y;
    As[ak + 2][am] = av.z; As[ak + 3][am] = av.w;
    *(float4*)&Bs[bk][bn] = bv;
    __syncthreads();
#pragma unroll
    for (int kk = 0; kk < 16; kk++) {  // strictly increasing k
      float4 a = *(const float4*)&As[kk][ty << 2];
      float4 b = *(const float4*)&Bs[kk][tx << 2];
      float aa[4] = {a.x, a.y, a.z, a.w};
      float bb[4] = {b.x, b.y, b.z, b.w};
#pragma unroll
      for (int i = 0; i < 4; i++)
#pragma unroll
        for (int j = 0; j < 4; j++) acc[i][j] = fmaf(aa[i], bb[j], acc[i][j]);
    }
  }
#pragma unroll
  for (int i = 0; i < 4; i++) {
    int r = row0 + (ty << 2) + i;
    if (r < N_NODES) {
      *(float4*)(H + (size_t)r * D_IN + col0 + (tx << 2)) =
          make_float4(acc[i][0], acc[i][1], acc[i][2], acc[i][3]);
      ushort4 s;
      s.x = f2bf(acc[i][0]); s.y = f2bf(acc[i][1]);
      s.z = f2bf(acc[i][2]); s.w = f2bf(acc[i][3]);
      *(ushort4*)(Hb + (size_t)r * D_IN + col0 + (tx << 2)) = s;
    }
  }
}

// ---------------------------------------------------------------------------
// P[c][o] = CB[c]·HW[:,o] in fp64 (stored fp32). Logit path only.
// ---------------------------------------------------------------------------
__global__ __launch_bounds__(256) void k_gemm_P(const float* __restrict__ CB,
                                                const float* __restrict__ HW,
                                                float* __restrict__ P) {
  __shared__ float As[16][68];
  __shared__ float Bs[16][68];
  const int tid = threadIdx.x;
  const int c0 = blockIdx.x * 64;
  const int o0 = blockIdx.y * 64;
  const int ty = tid >> 4, tx = tid & 15;
  const int am = tid >> 2, ak = (tid & 3) << 2;
  const int bk = tid >> 4, bn = (tid & 15) << 2;
  double acc[4][4] = {};
  for (int k0 = 0; k0 < D_IN; k0 += 16) {
    float4 av = *(const float4*)(CB + (size_t)(c0 + am) * D_IN + k0 + ak);
    float4 bv = *(const float4*)(HW + (size_t)(k0 + bk) * D_OUT + o0 + bn);
    __syncthreads();
    As[ak + 0][am] = av.x; As[ak + 1][am] = av.y;
    As[ak + 2][am] = av.z; As[ak + 3][am] = av.w;
    *(float4*)&Bs[bk][bn] = bv;
    __syncthreads();
#pragma unroll
    for (int kk = 0; kk < 16; kk++) {
      float4 a = *(const float4*)&As[kk][ty << 2];
      float4 b = *(const float4*)&Bs[kk][tx << 2];
      double aa[4] = {a.x, a.y, a.z, a.w};
      double bb[4] = {b.x, b.y, b.z, b.w};
#pragma unroll
      for (int i = 0; i < 4; i++)
#pragma unroll
        for (int j = 0; j < 4; j++) acc[i][j] = fma(aa[i], bb[j], acc[i][j]);
    }
  }
#pragma unroll
  for (int i = 0; i < 4; i++)
#pragma unroll
    for (int j = 0; j < 4; j++)
      P[(size_t)(c0 + (ty << 2) + i) * D_OUT + o0 + (tx << 2) + j] =
          (float)acc[i][j];
}

// ---------------------------------------------------------------------------
// MFMA candidate pass: approx scores s = cbsq - 2*(Hb@CBb^T) over all 2048
// codes; per row keep top-8 per 64-code half of each 128-tile (16 disjoint
// candidates). 128x128 tile, BK=128, 16x16x32 bf16 MFMA, swizzled LDS slabs.
// LDS: union{ A slab 32KB + B slab 32KB | Sc[128 codes][132 rows] 67.6KB }.
// ---------------------------------------------------------------------------
__global__ __launch_bounds__(256, 2) void k_mfma_cand(
    const unsigned short* __restrict__ Hb,
    const unsigned short* __restrict__ CBb,
    const float* __restrict__ CBSQ,
    float* __restrict__ candS, int* __restrict__ candI) {
  __shared__ __align__(16) char LDS_RAW[67584];
  float* Sc = (float*)LDS_RAW;
  const int tid  = threadIdx.x;
  const int lane = tid & 63, wave = tid >> 6;
  const int quad = lane >> 4, l16 = lane & 15;
  const int wy = wave >> 1, wx = wave & 1;
  const int row0 = blockIdx.x * 128;
  const int srow = tid >> 1, shalf = tid & 1;

  float rs[8]; int ri[8];
#pragma unroll
  for (int k = 0; k < 8; k++) { rs[k] = 3.4e38f; ri[k] = 0x7fffffff; }

  for (int ct = 0; ct < NUM_CODES / 128; ct++) {
    const int code0 = ct * 128;
    f32x4 acc[4][4];
#pragma unroll
    for (int rf = 0; rf < 4; rf++)
#pragma unroll
      for (int cf = 0; cf < 4; cf++)
        acc[rf][cf] = (f32x4){0.f, 0.f, 0.f, 0.f};

    for (int kb = 0; kb < 4; kb++) {  // BK = 128
      __syncthreads();                 // slabs (or Sc) free to overwrite
      // stage A(128 rows x 128 k) and B(128 codes x 128 k), bf16,
      // swizzled: addr(row,chunk) = chunk*2048 + ((row+2*chunk)&127)*16
#pragma unroll
      for (int it = 0; it < 8; it++) {
        int id = tid + it * 256;
        int arow = id >> 4, ac = id & 15;
        int grow = row0 + arow;
        uint4 v = make_uint4(0u, 0u, 0u, 0u);
        if (grow < N_NODES)
          v = *(const uint4*)(Hb + (size_t)grow * D_IN + kb * 128 + ac * 8);
        *(uint4*)(LDS_RAW + ac * 2048 + (((arow + 2 * ac) & 127) << 4)) = v;
        uint4 w = *(const uint4*)(CBb + (size_t)(code0 + arow) * D_IN +
                                  kb * 128 + ac * 8);
        *(uint4*)(LDS_RAW + 32768 + ac * 2048 +
                  (((arow + 2 * ac) & 127) << 4)) = w;
      }
      __syncthreads();
#pragma unroll
      for (int s = 0; s < 4; s++) {  // 4 MFMA k-steps of 32
        int cidx = s * 4 + quad;
        bf16x8 af[4], bf[4];
#pragma unroll
        for (int rf = 0; rf < 4; rf++) {
          int arow = wy * 64 + rf * 16 + l16;
          af[rf] = *(const bf16x8*)(LDS_RAW + cidx * 2048 +
                                    (((arow + 2 * cidx) & 127) << 4));
        }
#pragma unroll
        for (int cf = 0; cf < 4; cf++) {
          int brow = wx * 64 + cf * 16 + l16;
          bf[cf] = *(const bf16x8*)(LDS_RAW + 32768 + cidx * 2048 +
                                    (((brow + 2 * cidx) & 127) << 4));
        }
#pragma unroll
        for (int rf = 0; rf < 4; rf++)
#pragma unroll
          for (int cf = 0; cf < 4; cf++)
            acc[rf][cf] = __builtin_amdgcn_mfma_f32_16x16x32_bf16(
                af[rf], bf[cf], acc[rf][cf], 0, 0, 0);
      }
    }
    __syncthreads();  // K done, slabs dead -> Sc region reusable
    // scores -> Sc[code][132]; C/D layout: col=lane&15, row=quad*4+reg
#pragma unroll
    for (int cf = 0; cf < 4; cf++) {
      int code = wx * 64 + cf * 16 + l16;
      float cq = CBSQ[code0 + code];
#pragma unroll
      for (int rf = 0; rf < 4; rf++) {
        f32x4 sv;
#pragma unroll
        for (int r = 0; r < 4; r++) sv[r] = fmaf(-2.0f, acc[rf][cf][r], cq);
        int rowb = wy * 64 + rf * 16 + quad * 4;
        *(f32x4*)(Sc + (size_t)code * 132 + rowb) = sv;
      }
    }
    __syncthreads();
    // scan: thread (srow, shalf) scans 64 codes of its half for its row
    for (int i = 0; i < 64; i++) {
      int cl = shalf * 64 + i;
      float s = Sc[(size_t)cl * 132 + srow];
      int c = code0 + cl;
      if (better(s, c, rs[7], ri[7])) {
        rs[7] = s; ri[7] = c;
#pragma unroll
        for (int t = 7; t > 0; t--) {
          if (better(rs[t], ri[t], rs[t - 1], ri[t - 1])) {
            float tf = rs[t - 1]; rs[t - 1] = rs[t]; rs[t] = tf;
            int tc = ri[t - 1]; ri[t - 1] = ri[t]; ri[t] = tc;
          }
        }
      }
    }
  }
  int grow = row0 + srow;
  if (grow < N_NODES) {
#pragma unroll
    for (int k = 0; k < 8; k++) {
      candS[(size_t)grow * NCAND + shalf * 8 + k] = rs[k];
      candI[(size_t)grow * NCAND + shalf * 8 + k] = ri[k];
    }
  }
}

// ---------------------------------------------------------------------------
// np-exact rescore of candidates within RESCORE_MARGIN of the 4th-best approx
// score; exact fp32 sequential-k chain + np combine; top-4 (ties->lower idx).
// Block: 16 rows x 16 candidates.
// ---------------------------------------------------------------------------
__global__ __launch_bounds__(256) void k_rescore(
    const float* __restrict__ H, const float* __restrict__ CB,
    const float* __restrict__ CBSQ, const float* __restrict__ HSQ,
    const float* __restrict__ candS, const int* __restrict__ candI,
    int* __restrict__ cand4) {
  __shared__ float hs[16][516];
  __shared__ float ss[16][16];
  __shared__ int   ii[16][16];
  __shared__ float sres[16][16];
  const int tid = threadIdx.x;
  const int r0 = blockIdx.x * 16;
#pragma unroll
  for (int it = 0; it < 8; it++) {  // 2048 float4 tasks: coop-load 16 H rows
    int id = tid + it * 256;
    int row = id >> 7, f4 = id & 127;
    float4 v = *(const float4*)(H + (size_t)(r0 + row) * D_IN + f4 * 4);
    *(float4*)&hs[row][f4 * 4] = v;
  }
  {
    int row = tid >> 4, j = tid & 15;
    ss[row][j] = candS[(size_t)(r0 + row) * NCAND + j];
    ii[row][j] = candI[(size_t)(r0 + row) * NCAND + j];
  }
  __syncthreads();
  const int row = tid >> 4, j = tid & 15;
  // 4th-smallest approx score of this row's 16 candidates
  float m[4] = {3.4e38f, 3.4e38f, 3.4e38f, 3.4e38f};
  for (int t = 0; t < 16; t++) {
    float s = ss[row][t];
    if (s < m[3]) {
      m[3] = s;
#pragma unroll
      for (int u = 3; u > 0; u--)
        if (m[u] < m[u - 1]) { float tt = m[u - 1]; m[u - 1] = m[u]; m[u] = tt; }
    }
  }
  const float thr = m[3] + RESCORE_MARGIN;
  const float as = ss[row][j];
  const int ci = ii[row][j];
  float sc = 3.4e38f;
  if (as <= thr) {
    const float4* cbp = (const float4*)(CB + (size_t)ci * D_IN);
    float d = 0.f;
    for (int k = 0; k < 128; k++) {  // strict k order: single FMA chain
      float4 c4 = cbp[k];
      float4 h4 = *(const float4*)&hs[row][k * 4];
      d = fmaf(h4.x, c4.x, d);
      d = fmaf(h4.y, c4.y, d);
      d = fmaf(h4.z, c4.z, d);
      d = fmaf(h4.w, c4.w, d);
    }
    float t1 = __fsub_rn(HSQ[r0 + row], 2.0f * d);  // 2*d exact
    sc = __fadd_rn(t1, CBSQ[ci]);                   // np combine order
  }
  sres[row][j] = sc;
  __syncthreads();
  if (j == 0) {
    float bs[4]; int bi[4];
#pragma unroll
    for (int k = 0; k < 4; k++) { bs[k] = 3.4e38f; bi[k] = 0x7fffffff; }
    for (int t = 0; t < 16; t++) {
      float s = sres[row][t]; int c = ii[row][t];
      if (better(s, c, bs[3], bi[3])) {
        bs[3] = s; bi[3] = c;
#pragma unroll
        for (int u = 3; u > 0; u--) {
          if (better(bs[u], bi[u], bs[u - 1], bi[u - 1])) {
            float tf = bs[u - 1]; bs[u - 1] = bs[u]; bs[u] = tf;
            int tc = bi[u - 1]; bi[u - 1] = bi[u]; bi[u] = tc;
          }
        }
      }
    }
#pragma unroll
    for (int k = 0; k < 4; k++) cand4[(size_t)(r0 + row) * 4 + k] = bi[k];
  }
}

// ---------------------------------------------------------------------------
// OUT[row] = 0.25 * (P[c0]+P[c1]+P[c2]+P[c3]) + bias. One wave per row.
// ---------------------------------------------------------------------------
__global__ __launch_bounds__(256) void k_out(const int* __restrict__ cand4,
                                             const float* __restrict__ P,
                                             const float* __restrict__ HB,
                                             float* __restrict__ OUT) {
  const int lane = threadIdx.x & 63;
  const int row = blockIdx.x * 4 + (threadIdx.x >> 6);
  if (row >= N_NODES) return;
  const int c0 = cand4[(size_t)row * 4 + 0];
  const int c1 = cand4[(size_t)row * 4 + 1];
  const int c2 = cand4[(size_t)row * 4 + 2];
  const int c3 = cand4[(size_t)row * 4 + 3];
  const int col = lane << 2;
  float4 p0 = *(const float4*)(P + (size_t)c0 * D_OUT + col);
  float4 p1 = *(const float4*)(P + (size_t)c1 * D_OUT + col);
  float4 p2 = *(const float4*)(P + (size_t)c2 * D_OUT + col);
  float4 p3 = *(const float4*)(P + (size_t)c3 * D_OUT + col);
  float4 b = *(const float4*)(HB + col);
  float4 o;
  o.x = 0.25f * (((p0.x + p1.x) + p2.x) + p3.x) + b.x;
  o.y = 0.25f * (((p0.y + p1.y) + p2.y) + p3.y) + b.y;
  o.z = 0.25f * (((p0.z + p1.z) + p2.z) + p3.z) + b.z;
  o.w = 0.25f * (((p0.w + p1.w) + p2.w) + p3.w) + b.w;
  *(float4*)(OUT + (size_t)row * D_OUT + col) = o;
}

// ---------------------------------------------------------------------------
extern "C" void kernel_launch(void* const* d_in, const int* in_sizes, int n_in,
                              void* d_out, int out_size, void* d_ws,
                              size_t ws_size, hipStream_t stream) {
  const float* X  = (const float*)d_in[0];
  const float* LP = (const float*)d_in[1];
  const float* CB = (const float*)d_in[2];
  const float* HW = (const float*)d_in[3];
  const float* HB = (const float*)d_in[4];
  float* OUT = (float*)d_out;

  // d_out (100000*256*4 B) doubles as Hb (100000*512*2 B bf16, exact fit);
  // Hb fully consumed by k_mfma_cand before k_out overwrites.
  unsigned short* Hb = (unsigned short*)d_out;

  char* ws = (char*)d_ws;
  size_t off = 0;
  float* H = (float*)(ws + off);      off += (size_t)N_NODES * D_IN * 4;     // 204.8 MB
  float* P = (float*)(ws + off);      off += (size_t)NUM_CODES * D_OUT * 4;  // 2 MB
  unsigned short* CBb = (unsigned short*)(ws + off);
  off += (size_t)NUM_CODES * D_IN * 2;                                       // 2 MB
  float* CBSQ = (float*)(ws + off);   off += (size_t)NUM_CODES * 4;
  float* HSQ = (float*)(ws + off);    off += (size_t)N_NODES * 4;
  off = (off + 255) & ~(size_t)255;
  float* candS = (float*)(ws + off);  off += (size_t)N_NODES * NCAND * 4;    // 6.4 MB
  int* candI = (int*)(ws + off);      off += (size_t)N_NODES * NCAND * 4;    // 6.4 MB
  int* cand4 = (int*)(ws + off);      off += (size_t)N_NODES * 4 * 4;        // 1.6 MB
  // total ~224 MB

  const int row64 = (N_NODES + 63) / 64;
  const int row128 = (N_NODES + 127) / 128;

  k_rowsq<<<(NUM_CODES + 255) / 256, 256, 0, stream>>>(CB, NUM_CODES, CBSQ);
  k_cb2bf<<<NUM_CODES * D_IN / 1024, 256, 0, stream>>>(CB, CBb);
  k_gemm_P<<<dim3(NUM_CODES / 64, D_OUT / 64), 256, 0, stream>>>(CB, HW, P);
  k_h_np<<<dim3(row64, D_IN / 64), 256, 0, stream>>>(X, LP, H, Hb);
  k_rowsq<<<(N_NODES + 255) / 256, 256, 0, stream>>>(H, N_NODES, HSQ);
  k_mfma_cand<<<row128, 256, 0, stream>>>(Hb, CBb, CBSQ, candS, candI);
  k_rescore<<<N_NODES / 16, 256, 0, stream>>>(H, CB, CBSQ, HSQ, candS, candI,
                                              cand4);
  k_out<<<N_NODES / 4, 256, 0, stream>>>(cand4, P, HB, OUT);
}